// Round 3
// baseline (484.139 us; speedup 1.0000x reference)
//
#include <hip/hip_runtime.h>
#include <hip/hip_bf16.h>
#include <stdint.h>

// Round 9: LDS-bandwidth attack. Round 8 fixed HBM traffic (FETCH 245->27MB)
// but dur was flat -> bottleneck is on-CU: per block-iter, 8 waves re-read
// the same 32KB K/V tile (320 KB LDS reads = ~3765 cyc = 54% of the 6950-cyc
// iter) + VALU 35%. Per-wave K/V LDS traffic scales as 1/(rows per wave), so:
//   flash -> 4 waves x 64 q-rows (4 q-groups), 256 rows/block (grid unchanged)
//   -> LDS traffic/CU-iter halves (192 KB); 1 wave/SIMD, ILP overlaps
//   VALU||MFMA||LDS (MFMA is fire-and-forget on the matrix pipe).
//   o[4][8]+qf[4][4]+s[4][4] ~ 300 VGPR -> __launch_bounds__(256,1).
//   VALU cut: fold log2e into Q pre-scale, raw v_exp_f32 (exp2) -- deletes
//   64 v_mul per wave-iter. XCD swizzles (round 8) kept everywhere.
//
// ws layout:
//   xb      [8192][1024] bf16  @ 0         (dead after qkv -> Ob)
//   wqkv_t  [3072][1024] bf16  @ 16777216  (dead after qkv -> mbits)
//   wout_t  [1024][1024] bf16  @ 23068672
//   Qs      [16][4096][128]    @ 25165824
//   Ks      [16][4096][128]    @ 41943040
//   Vt      [16][128][4096]    @ 58720256

typedef __attribute__((ext_vector_type(8))) short short8;
typedef __attribute__((ext_vector_type(4))) float f32x4;

// DIM^-0.5 * log2(e) = (1/32) * 1.44269504 : S is computed in log2 domain,
// exp via raw v_exp_f32 (exp2). Masked lanes get -1e30 -> exp2 -> 0.
#define SCALE_Q 0.0450842200f

__device__ __forceinline__ unsigned short f2bf(float f) {
  union { float f; unsigned int u; } v;
  v.f = f;
  return (unsigned short)((v.u + 0x7fffu + ((v.u >> 16) & 1u)) >> 16);
}

__device__ __forceinline__ unsigned int pkbf2(float a, float b) {
  __hip_bfloat162 h = __float22bfloat162_rn(make_float2(a, b));
  union { __hip_bfloat162 h; unsigned int u; } c;
  c.h = h;
  return c.u;
}

__device__ __forceinline__ void gload_lds16(const void* g, void* l) {
  __builtin_amdgcn_global_load_lds(
      (const __attribute__((address_space(1))) uint32_t*)(uintptr_t)g,
      (__attribute__((address_space(3))) uint32_t*)(uintptr_t)l, 16, 0, 0);
}

__device__ __forceinline__ f32x4 zero4() {
  f32x4 z; z.x = 0.f; z.y = 0.f; z.z = 0.f; z.w = 0.f; return z;
}

// ---------------- conversions ----------------
__global__ __launch_bounds__(256) void k_cvt_x(const float* __restrict__ in,
                                               unsigned short* __restrict__ out) {
  const int t = blockIdx.x * 256 + threadIdx.x;
  const float4 v = ((const float4*)in)[t];
  ushort4 o;
  o.x = f2bf(v.x); o.y = f2bf(v.y); o.z = f2bf(v.z); o.w = f2bf(v.w);
  ((ushort4*)out)[t] = o;
}

__global__ __launch_bounds__(256) void k_cvt_wt(const float* __restrict__ w,
                                                unsigned short* __restrict__ wt,
                                                int Nn) {
  __shared__ float t[32][33];
  const int n0 = blockIdx.x << 5, k0 = blockIdx.y << 5;
  const int c = threadIdx.x & 31, r8 = threadIdx.x >> 5;
#pragma unroll
  for (int i = 0; i < 4; ++i) {
    const int r = (i << 3) + r8;
    t[r][c] = w[(long)(k0 + r) * Nn + n0 + c];
  }
  __syncthreads();
#pragma unroll
  for (int i = 0; i < 4; ++i) {
    const int r = (i << 3) + r8;
    wt[(long)(n0 + r) * 1024 + k0 + c] = f2bf(t[c][r]);
  }
}

// ---------------- mask -> bitmask (ballot) ----------------
__global__ __launch_bounds__(256) void k_mask_bits(
    const int* __restrict__ m, unsigned long long* __restrict__ mb) {
  const int t = blockIdx.x * 256 + threadIdx.x;
  const unsigned long long b = __ballot(m[t] != 0);
  if ((threadIdx.x & 63) == 0) mb[t >> 6] = b;
}

// ---------------- QKV GEMM ----------------
__global__ __launch_bounds__(256, 2) void k_qkv_gemm(
    const unsigned short* __restrict__ A,   // [8192][1024]
    const unsigned short* __restrict__ Bt,  // [3072][1024]
    unsigned short* __restrict__ Qs, unsigned short* __restrict__ Ks,
    unsigned short* __restrict__ Vt) {
  __shared__ __align__(16) unsigned short lA[4][128][8];
  __shared__ __align__(16) unsigned short lB[4][128][8];
  const int tid = threadIdx.x;
  const int w = tid >> 6, ln = tid & 63;
  const int m15 = ln & 15, q4 = ln >> 4;
  const int wm = (w >> 1) << 6, wn = (w & 1) << 6;
  const int id = blockIdx.x;
  const int swz = (id & 7) * 192 + (id >> 3);   // XCD-chunked remap
  const int tn = swz % 24, tm = swz / 24;
  const int which = tn >> 3;   // 0=Q 1=K 2=V (uniform per block)
  const int h = tn & 7;

  f32x4 acc[4][4];
#pragma unroll
  for (int i = 0; i < 4; ++i)
#pragma unroll
    for (int j = 0; j < 4; ++j) acc[i][j] = zero4();

  if (which == 2) {
    for (int kb = 0; kb < 1024; kb += 32) {
      __syncthreads();
#pragma unroll
      for (int c = 0; c < 2; ++c) {
        const int p = ((c * 4 + w) << 10) + (ln << 4);
        const int g = p >> 11;
        const int r = (p & 2047) >> 4;
        gload_lds16(A + ((long)tm * 128 + r) * 1024 + kb + g * 8,
                    (char*)&lA[0][0][0] + p);
        gload_lds16(Bt + ((long)tn * 128 + r) * 1024 + kb + g * 8,
                    (char*)&lB[0][0][0] + p);
      }
      __syncthreads();
      short8 afr[4], bfr[4];
#pragma unroll
      for (int i = 0; i < 4; ++i)
        afr[i] = *(const short8*)&lA[q4][wm + i * 16 + m15][0];
#pragma unroll
      for (int j = 0; j < 4; ++j)
        bfr[j] = *(const short8*)&lB[q4][wn + j * 16 + m15][0];
#pragma unroll
      for (int i = 0; i < 4; ++i)
#pragma unroll
        for (int j = 0; j < 4; ++j)
          acc[i][j] = __builtin_amdgcn_mfma_f32_16x16x32_bf16(afr[i], bfr[j],
                                                              acc[i][j], 0, 0, 0);
    }
#pragma unroll
    for (int i = 0; i < 4; ++i) {
      const int m0 = (tm << 7) + wm + (i << 4) + (q4 << 2);
      const int b = m0 >> 12, row0 = m0 & 4095;
#pragma unroll
      for (int j = 0; j < 4; ++j) {
        const int dd = wn + (j << 4) + m15;
        const long bh = b * 8 + h;
        uint2 u;
        u.x = pkbf2(acc[i][j][0], acc[i][j][1]);
        u.y = pkbf2(acc[i][j][2], acc[i][j][3]);
        *(uint2*)&Vt[(bh * 128 + dd) * 4096 + row0] = u;
      }
    }
  } else {
    for (int kb = 0; kb < 1024; kb += 32) {
      __syncthreads();
#pragma unroll
      for (int c = 0; c < 2; ++c) {
        const int p = ((c * 4 + w) << 10) + (ln << 4);
        const int g = p >> 11;
        const int r = (p & 2047) >> 4;
        gload_lds16(A + ((long)tm * 128 + r) * 1024 + kb + g * 8,
                    (char*)&lA[0][0][0] + p);
        gload_lds16(Bt + ((long)tn * 128 + r) * 1024 + kb + g * 8,
                    (char*)&lB[0][0][0] + p);
      }
      __syncthreads();
      short8 afr[4], bfr[4];
#pragma unroll
      for (int i = 0; i < 4; ++i)
        afr[i] = *(const short8*)&lA[q4][wm + i * 16 + m15][0];
#pragma unroll
      for (int j = 0; j < 4; ++j)
        bfr[j] = *(const short8*)&lB[q4][wn + j * 16 + m15][0];
#pragma unroll
      for (int i = 0; i < 4; ++i)
#pragma unroll
        for (int j = 0; j < 4; ++j)
          acc[i][j] = __builtin_amdgcn_mfma_f32_16x16x32_bf16(bfr[j], afr[i],
                                                              acc[i][j], 0, 0, 0);
    }
    unsigned short* Dst = (which == 0) ? Qs : Ks;
    const float sc = (which == 0) ? SCALE_Q : 1.0f;
#pragma unroll
    for (int i = 0; i < 4; ++i) {
      const int m = (tm << 7) + wm + (i << 4) + m15;
      const int b = m >> 12, row = m & 4095;
      const long bh = b * 8 + h;
#pragma unroll
      for (int j = 0; j < 4; ++j) {
        const int dd0 = wn + (j << 4) + (q4 << 2);
        uint2 u;
        u.x = pkbf2(acc[i][j][0] * sc, acc[i][j][1] * sc);
        u.y = pkbf2(acc[i][j][2] * sc, acc[i][j][3] * sc);
        *(uint2*)&Dst[(bh * 4096 + row) * 128 + dd0] = u;
      }
    }
  }
}

// ---------------- flash attention ----------------
// 4 waves x 64 rows = 256 rows/block; flat grid 256, XCD x owns bh {2x,2x+1}.
// 1 wave/SIMD; ILP overlaps MFMA (fire-and-forget) with VALU + LDS.
__global__ __launch_bounds__(256, 1) void k_flash(
    const unsigned short* __restrict__ Qs, const unsigned short* __restrict__ Ks,
    const unsigned short* __restrict__ Vt,
    const unsigned long long* __restrict__ mbits,
    unsigned short* __restrict__ Ob) {
  __shared__ __align__(16) unsigned short lK[2][16][64][8];   // 2 x 16 KB
  __shared__ __align__(16) unsigned short lV[2][8][128][8];   // 2 x 16 KB
  __shared__ __align__(16) unsigned short lP[4][4][16][72];   // 36 KB

  const int tid = threadIdx.x;
  const int w = tid >> 6, ln = tid & 63;
  const int m15 = ln & 15, q4 = ln >> 4;
  const int id = blockIdx.x;
  const int xcd = id & 7, jj = id >> 3;
  const int bh = (xcd << 1) | (jj >> 4);   // 2 bh per XCD
  const int rowblk = jj & 15;
  const int rbase = rowblk * 256 + w * 64;

  const unsigned short* Qbh = Qs + (long)bh * 524288;
  const unsigned short* Kbh = Ks + (long)bh * 524288;
  const unsigned short* Vbh = Vt + (long)bh * 524288;

  short8 qf[4][4];
#pragma unroll
  for (int qg = 0; qg < 4; ++qg)
#pragma unroll
    for (int kk = 0; kk < 4; ++kk)
      qf[qg][kk] = *(const short8*)(Qbh + (long)(rbase + qg * 16 + m15) * 128 +
                                    kk * 32 + q4 * 8);

  f32x4 o[4][8];
#pragma unroll
  for (int qg = 0; qg < 4; ++qg)
#pragma unroll
    for (int j = 0; j < 8; ++j) o[qg][j] = zero4();
  f32x4 lacc[4];
#pragma unroll
  for (int qg = 0; qg < 4; ++qg) lacc[qg] = zero4();

  const bool maskblk = rowblk < 8;   // rows 0..2047

#define STAGE_KV(dst, kvoff)                                              \
  {                                                                       \
    _Pragma("unroll")                                                     \
    for (int c = 0; c < 4; ++c) {                                         \
      const int p = ((c * 4 + w) << 10) + (ln << 4);                      \
      const int cs = p >> 10;                                             \
      const int j = (p & 1023) >> 4;                                      \
      gload_lds16(Kbh + (long)((kvoff) + j) * 128 + cs * 8,               \
                  (char*)&lK[dst][0][0][0] + p);                          \
    }                                                                     \
    _Pragma("unroll")                                                     \
    for (int c = 0; c < 4; ++c) {                                         \
      const int p = ((c * 4 + w) << 10) + (ln << 4);                      \
      const int cv = p >> 11;                                             \
      const int dv = (p & 2047) >> 4;                                     \
      gload_lds16(Vbh + (long)dv * 4096 + (kvoff) + cv * 8,               \
                  (char*)&lV[dst][0][0][0] + p);                          \
    }                                                                     \
  }

  // prologue: stage tile 0 into buf 0 (syncthreads drains vmcnt)
  STAGE_KV(0, 0);
  __syncthreads();

  int cur = 0;
  for (int kv = 0; kv < 4096; kv += 64) {
    // mask words FIRST (so their wait leaves the prefetch in flight)
    unsigned long long mw[4];
    const bool domask = maskblk && (kv < 2048);
    if (domask) {
#pragma unroll
      for (int qg = 0; qg < 4; ++qg)
        mw[qg] = mbits[(long)(rbase + qg * 16 + m15) * 32 + (kv >> 6)];
    }

    // prefetch next tile into the other buffer
    const int nb = cur ^ 1;
    if (kv + 64 < 4096) STAGE_KV(nb, kv + 64);

    // S^T = K Q^T : s[qg][jt] lane layout col=m15 (q-row), row=q4*4+r (j)
    f32x4 s[4][4];
#pragma unroll
    for (int qg = 0; qg < 4; ++qg)
#pragma unroll
      for (int jt = 0; jt < 4; ++jt) s[qg][jt] = zero4();
    __builtin_amdgcn_s_setprio(1);
#pragma unroll
    for (int jt = 0; jt < 4; ++jt) {
#pragma unroll
      for (int kk = 0; kk < 4; ++kk) {
        const short8 kfr = *(const short8*)&lK[cur][kk * 4 + q4][jt * 16 + m15][0];
#pragma unroll
        for (int qg = 0; qg < 4; ++qg)
          s[qg][jt] = __builtin_amdgcn_mfma_f32_16x16x32_bf16(kfr, qf[qg][kk],
                                                              s[qg][jt], 0, 0, 0);
      }
    }
    __builtin_amdgcn_s_setprio(0);

    if (domask) {
#pragma unroll
      for (int qg = 0; qg < 4; ++qg) {
#pragma unroll
        for (int jt = 0; jt < 4; ++jt) {
          const unsigned int u =
              (jt & 2) ? (unsigned int)(mw[qg] >> 32) : (unsigned int)mw[qg];
          const int base = ((jt & 1) << 4) + (q4 << 2);
#pragma unroll
          for (int r = 0; r < 4; ++r) {
            if (!((u >> (base + r)) & 1u)) s[qg][jt][r] = -1e30f;
          }
        }
      }
    }

    // p = exp2(s) (log2e folded into Q scale); accumulate l; pack to
    // wave-private LDS as PV A-frags.
#pragma unroll
    for (int qg = 0; qg < 4; ++qg) {
#pragma unroll
      for (int jt = 0; jt < 4; ++jt) {
        f32x4 p;
        p.x = __builtin_amdgcn_exp2f(s[qg][jt].x);
        p.y = __builtin_amdgcn_exp2f(s[qg][jt].y);
        p.z = __builtin_amdgcn_exp2f(s[qg][jt].z);
        p.w = __builtin_amdgcn_exp2f(s[qg][jt].w);
        lacc[qg] += p;
        uint2 u;
        u.x = pkbf2(p.x, p.y);
        u.y = pkbf2(p.z, p.w);
        *(uint2*)&lP[w][qg][m15][jt * 16 + q4 * 4] = u;
      }
    }
    __asm__ volatile("s_waitcnt lgkmcnt(0)" ::: "memory");
    __builtin_amdgcn_sched_barrier(0);

    // O += P @ V  (each V-frag read feeds all 4 q-groups)
    __builtin_amdgcn_s_setprio(1);
#pragma unroll
    for (int kk2 = 0; kk2 < 2; ++kk2) {
      short8 pf[4];
#pragma unroll
      for (int qg = 0; qg < 4; ++qg)
        pf[qg] = *(const short8*)&lP[w][qg][m15][kk2 * 32 + q4 * 8];
#pragma unroll
      for (int jt2 = 0; jt2 < 8; ++jt2) {
        const short8 vf = *(const short8*)&lV[cur][kk2 * 4 + q4][jt2 * 16 + m15][0];
#pragma unroll
        for (int qg = 0; qg < 4; ++qg)
          o[qg][jt2] = __builtin_amdgcn_mfma_f32_16x16x32_bf16(pf[qg], vf,
                                                               o[qg][jt2], 0, 0, 0);
      }
    }
    __builtin_amdgcn_s_setprio(0);

    // single barrier: drains this iter's prefetch -> next tile ready,
    // prev buffer free to overwrite
    __syncthreads();
    cur = nb;
  }
#undef STAGE_KV

  const int b = bh >> 3, h = bh & 7;
#pragma unroll
  for (int qg = 0; qg < 4; ++qg) {
    float lh = lacc[qg].x + lacc[qg].y + lacc[qg].z + lacc[qg].w;
    lh += __shfl_xor(lh, 16);
    lh += __shfl_xor(lh, 32);
    const float linv = 1.0f / lh;
#pragma unroll
    for (int r = 0; r < 4; ++r) {
      const float li = __shfl(linv, q4 * 4 + r);
      const int row = rbase + qg * 16 + q4 * 4 + r;
      unsigned short* op = Ob + ((long)(b * 4096 + row)) * 1024 + h * 128;
#pragma unroll
      for (int jt2 = 0; jt2 < 8; ++jt2)
        op[jt2 * 16 + m15] = f2bf(o[qg][jt2][r] * li);
    }
  }
}

// ---------------- out projection ----------------
__global__ __launch_bounds__(256, 2) void k_proj_gemm(
    const unsigned short* __restrict__ A,   // [8192][1024]
    const unsigned short* __restrict__ Bt,  // [1024][1024]
    const float* __restrict__ bias, float* __restrict__ Out) {
  __shared__ __align__(16) unsigned short lA[4][128][8];
  __shared__ __align__(16) unsigned short lB[4][128][8];
  const int tid = threadIdx.x;
  const int w = tid >> 6, ln = tid & 63;
  const int m15 = ln & 15, q4 = ln >> 4;
  const int wm = (w >> 1) << 6, wn = (w & 1) << 6;
  const int id = blockIdx.x;
  const int swz = (id & 7) * 64 + (id >> 3);
  const int tn = swz & 7, tm = swz >> 3;

  f32x4 acc[4][4];
#pragma unroll
  for (int i = 0; i < 4; ++i)
#pragma unroll
    for (int j = 0; j < 4; ++j) acc[i][j] = zero4();

  for (int kb = 0; kb < 1024; kb += 32) {
    __syncthreads();
#pragma unroll
    for (int c = 0; c < 2; ++c) {
      const int p = ((c * 4 + w) << 10) + (ln << 4);
      const int g = p >> 11;
      const int r = (p & 2047) >> 4;
      gload_lds16(A + ((long)tm * 128 + r) * 1024 + kb + g * 8,
                  (char*)&lA[0][0][0] + p);
      gload_lds16(Bt + ((long)tn * 128 + r) * 1024 + kb + g * 8,
                  (char*)&lB[0][0][0] + p);
    }
    __syncthreads();
    short8 afr[4], bfr[4];
#pragma unroll
    for (int i = 0; i < 4; ++i)
      afr[i] = *(const short8*)&lA[q4][wm + i * 16 + m15][0];
#pragma unroll
    for (int j = 0; j < 4; ++j)
      bfr[j] = *(const short8*)&lB[q4][wn + j * 16 + m15][0];
#pragma unroll
    for (int i = 0; i < 4; ++i)
#pragma unroll
      for (int j = 0; j < 4; ++j)
        acc[i][j] = __builtin_amdgcn_mfma_f32_16x16x32_bf16(afr[i], bfr[j],
                                                            acc[i][j], 0, 0, 0);
  }

#pragma unroll
  for (int i = 0; i < 4; ++i)
#pragma unroll
    for (int r = 0; r < 4; ++r) {
      const int m = (tm << 7) + wm + (i << 4) + (q4 << 2) + r;
#pragma unroll
      for (int j = 0; j < 4; ++j) {
        const int n = (tn << 7) + wn + (j << 4) + m15;
        Out[(long)m * 1024 + n] = acc[i][j][r] + bias[n];
      }
    }
}

extern "C" void kernel_launch(void* const* d_in, const int* in_sizes, int n_in,
                              void* d_out, int out_size, void* d_ws,
                              size_t ws_size, hipStream_t stream) {
  const float* x = (const float*)d_in[0];
  const float* Wqkv = (const float*)d_in[1];
  const float* Wout = (const float*)d_in[2];
  const float* bout = (const float*)d_in[3];
  const int* mask = (const int*)d_in[4];
  float* out = (float*)d_out;

  char* ws = (char*)d_ws;
  unsigned short* xb     = (unsigned short*)(ws);            // later Ob
  unsigned short* wqkv_t = (unsigned short*)(ws + 16777216);
  unsigned short* wout_t = (unsigned short*)(ws + 23068672);
  unsigned short* Qs     = (unsigned short*)(ws + 25165824);
  unsigned short* Ks     = (unsigned short*)(ws + 41943040);
  unsigned short* Vt     = (unsigned short*)(ws + 58720256);
  unsigned short* Ob     = xb;                         // xb dead after qkv
  unsigned long long* mbits = (unsigned long long*)wqkv_t;  // wqkv_t dead after qkv

  hipLaunchKernelGGL(k_cvt_x, dim3(8192), dim3(256), 0, stream, x, xb);
  hipLaunchKernelGGL(k_cvt_wt, dim3(96, 32), dim3(256), 0, stream, Wqkv, wqkv_t, 3072);
  hipLaunchKernelGGL(k_cvt_wt, dim3(32, 32), dim3(256), 0, stream, Wout, wout_t, 1024);
  hipLaunchKernelGGL(k_qkv_gemm, dim3(1536), dim3(256), 0, stream,
                     xb, wqkv_t, Qs, Ks, Vt);
  hipLaunchKernelGGL(k_mask_bits, dim3(16384), dim3(256), 0, stream,
                     mask, mbits);
  hipLaunchKernelGGL(k_flash, dim3(256), dim3(256), 0, stream,
                     Qs, Ks, Vt, mbits, Ob);
  hipLaunchKernelGGL(k_proj_gemm, dim3(512), dim3(256), 0, stream,
                     Ob, wout_t, bout, out);
}

// Round 5
// 430.951 us; speedup vs baseline: 1.1234x; 1.1234x over previous
//
#include <hip/hip_runtime.h>
#include <hip/hip_bf16.h>
#include <stdint.h>

// Round 11 = round 10 resubmit (bench was an infra failure: "container
// failed twice", no kernel verdict). Kernel re-audited: uniform barriers,
// consistent A/B slot maps (permutation-safe), HW-verified 32x32 C/D
// layout (m74/m101), all workspace bounds checked. No code change.
//
// Round 10 design: revert round 9's 1-wave/SIMD experiment (TLP loss
// exposed all waits; m114 lesson). New flash: 32x32x16 MFMA + T12
// in-register P exchange (shfl_xor(32) emulation of permlane32_swap):
//  - lP LDS roundtrip deleted (no ds_write/read of P, no lgkm sync, -36KB)
//  - LDS 64KB -> 2 independent blocks/CU (4 waves x 32 rows, 512 blocks):
//    one block's vmcnt-drain at its barrier hides under the other block's
//    compute (round 8 had 1 block/CU -> drain fully exposed)
//  - MFMA issue slots halve (32x 32x32x16 vs 64x 16x16x32)
// S^T = mfma32(K, Q): C/D col=lane&31=q, row(kv)=(r&3)+8*(r>>2)+4*hi.
//
// ws layout:
//   xb      [8192][1024] bf16  @ 0         (dead after qkv -> Ob)
//   wqkv_t  [3072][1024] bf16  @ 16777216  (dead after qkv -> mbits)
//   wout_t  [1024][1024] bf16  @ 23068672
//   Qs      [16][4096][128]    @ 25165824
//   Ks      [16][4096][128]    @ 41943040
//   Vt      [16][128][4096]    @ 58720256

typedef __attribute__((ext_vector_type(8))) short short8;
typedef __attribute__((ext_vector_type(4))) float f32x4;
typedef __attribute__((ext_vector_type(16))) float f32x16;

// DIM^-0.5 * log2(e): S computed in log2 domain, exp via exp2.
#define SCALE_Q 0.0450842200f

__device__ __forceinline__ unsigned short f2bf(float f) {
  union { float f; unsigned int u; } v;
  v.f = f;
  return (unsigned short)((v.u + 0x7fffu + ((v.u >> 16) & 1u)) >> 16);
}

__device__ __forceinline__ unsigned int pkbf2(float a, float b) {
  __hip_bfloat162 h = __float22bfloat162_rn(make_float2(a, b));
  union { __hip_bfloat162 h; unsigned int u; } c;
  c.h = h;
  return c.u;
}

__device__ __forceinline__ void gload_lds16(const void* g, void* l) {
  __builtin_amdgcn_global_load_lds(
      (const __attribute__((address_space(1))) uint32_t*)(uintptr_t)g,
      (__attribute__((address_space(3))) uint32_t*)(uintptr_t)l, 16, 0, 0);
}

__device__ __forceinline__ f32x4 zero4() {
  f32x4 z; z.x = 0.f; z.y = 0.f; z.z = 0.f; z.w = 0.f; return z;
}

// ---------------- conversions ----------------
__global__ __launch_bounds__(256) void k_cvt_x(const float* __restrict__ in,
                                               unsigned short* __restrict__ out) {
  const int t = blockIdx.x * 256 + threadIdx.x;
  const float4 v = ((const float4*)in)[t];
  ushort4 o;
  o.x = f2bf(v.x); o.y = f2bf(v.y); o.z = f2bf(v.z); o.w = f2bf(v.w);
  ((ushort4*)out)[t] = o;
}

__global__ __launch_bounds__(256) void k_cvt_wt(const float* __restrict__ w,
                                                unsigned short* __restrict__ wt,
                                                int Nn) {
  __shared__ float t[32][33];
  const int n0 = blockIdx.x << 5, k0 = blockIdx.y << 5;
  const int c = threadIdx.x & 31, r8 = threadIdx.x >> 5;
#pragma unroll
  for (int i = 0; i < 4; ++i) {
    const int r = (i << 3) + r8;
    t[r][c] = w[(long)(k0 + r) * Nn + n0 + c];
  }
  __syncthreads();
#pragma unroll
  for (int i = 0; i < 4; ++i) {
    const int r = (i << 3) + r8;
    wt[(long)(n0 + r) * 1024 + k0 + c] = f2bf(t[c][r]);
  }
}

// ---------------- mask -> bitmask (ballot) ----------------
__global__ __launch_bounds__(256) void k_mask_bits(
    const int* __restrict__ m, unsigned long long* __restrict__ mb) {
  const int t = blockIdx.x * 256 + threadIdx.x;
  const unsigned long long b = __ballot(m[t] != 0);
  if ((threadIdx.x & 63) == 0) mb[t >> 6] = b;
}

// ---------------- QKV GEMM ----------------
__global__ __launch_bounds__(256, 2) void k_qkv_gemm(
    const unsigned short* __restrict__ A,   // [8192][1024]
    const unsigned short* __restrict__ Bt,  // [3072][1024]
    unsigned short* __restrict__ Qs, unsigned short* __restrict__ Ks,
    unsigned short* __restrict__ Vt) {
  __shared__ __align__(16) unsigned short lA[4][128][8];
  __shared__ __align__(16) unsigned short lB[4][128][8];
  const int tid = threadIdx.x;
  const int w = tid >> 6, ln = tid & 63;
  const int m15 = ln & 15, q4 = ln >> 4;
  const int wm = (w >> 1) << 6, wn = (w & 1) << 6;
  const int id = blockIdx.x;
  const int swz = (id & 7) * 192 + (id >> 3);   // XCD-chunked remap
  const int tn = swz % 24, tm = swz / 24;
  const int which = tn >> 3;   // 0=Q 1=K 2=V (uniform per block)
  const int h = tn & 7;

  f32x4 acc[4][4];
#pragma unroll
  for (int i = 0; i < 4; ++i)
#pragma unroll
    for (int j = 0; j < 4; ++j) acc[i][j] = zero4();

  if (which == 2) {
    for (int kb = 0; kb < 1024; kb += 32) {
      __syncthreads();
#pragma unroll
      for (int c = 0; c < 2; ++c) {
        const int p = ((c * 4 + w) << 10) + (ln << 4);
        const int g = p >> 11;
        const int r = (p & 2047) >> 4;
        gload_lds16(A + ((long)tm * 128 + r) * 1024 + kb + g * 8,
                    (char*)&lA[0][0][0] + p);
        gload_lds16(Bt + ((long)tn * 128 + r) * 1024 + kb + g * 8,
                    (char*)&lB[0][0][0] + p);
      }
      __syncthreads();
      short8 afr[4], bfr[4];
#pragma unroll
      for (int i = 0; i < 4; ++i)
        afr[i] = *(const short8*)&lA[q4][wm + i * 16 + m15][0];
#pragma unroll
      for (int j = 0; j < 4; ++j)
        bfr[j] = *(const short8*)&lB[q4][wn + j * 16 + m15][0];
#pragma unroll
      for (int i = 0; i < 4; ++i)
#pragma unroll
        for (int j = 0; j < 4; ++j)
          acc[i][j] = __builtin_amdgcn_mfma_f32_16x16x32_bf16(afr[i], bfr[j],
                                                              acc[i][j], 0, 0, 0);
    }
#pragma unroll
    for (int i = 0; i < 4; ++i) {
      const int m0 = (tm << 7) + wm + (i << 4) + (q4 << 2);
      const int b = m0 >> 12, row0 = m0 & 4095;
#pragma unroll
      for (int j = 0; j < 4; ++j) {
        const int dd = wn + (j << 4) + m15;
        const long bh = b * 8 + h;
        uint2 u;
        u.x = pkbf2(acc[i][j][0], acc[i][j][1]);
        u.y = pkbf2(acc[i][j][2], acc[i][j][3]);
        *(uint2*)&Vt[(bh * 128 + dd) * 4096 + row0] = u;
      }
    }
  } else {
    for (int kb = 0; kb < 1024; kb += 32) {
      __syncthreads();
#pragma unroll
      for (int c = 0; c < 2; ++c) {
        const int p = ((c * 4 + w) << 10) + (ln << 4);
        const int g = p >> 11;
        const int r = (p & 2047) >> 4;
        gload_lds16(A + ((long)tm * 128 + r) * 1024 + kb + g * 8,
                    (char*)&lA[0][0][0] + p);
        gload_lds16(Bt + ((long)tn * 128 + r) * 1024 + kb + g * 8,
                    (char*)&lB[0][0][0] + p);
      }
      __syncthreads();
      short8 afr[4], bfr[4];
#pragma unroll
      for (int i = 0; i < 4; ++i)
        afr[i] = *(const short8*)&lA[q4][wm + i * 16 + m15][0];
#pragma unroll
      for (int j = 0; j < 4; ++j)
        bfr[j] = *(const short8*)&lB[q4][wn + j * 16 + m15][0];
#pragma unroll
      for (int i = 0; i < 4; ++i)
#pragma unroll
        for (int j = 0; j < 4; ++j)
          acc[i][j] = __builtin_amdgcn_mfma_f32_16x16x32_bf16(bfr[j], afr[i],
                                                              acc[i][j], 0, 0, 0);
    }
    unsigned short* Dst = (which == 0) ? Qs : Ks;
    const float sc = (which == 0) ? SCALE_Q : 1.0f;
#pragma unroll
    for (int i = 0; i < 4; ++i) {
      const int m = (tm << 7) + wm + (i << 4) + m15;
      const int b = m >> 12, row = m & 4095;
      const long bh = b * 8 + h;
#pragma unroll
      for (int j = 0; j < 4; ++j) {
        const int dd0 = wn + (j << 4) + (q4 << 2);
        uint2 u;
        u.x = pkbf2(acc[i][j][0] * sc, acc[i][j][1] * sc);
        u.y = pkbf2(acc[i][j][2] * sc, acc[i][j][3] * sc);
        *(uint2*)&Dst[(bh * 4096 + row) * 128 + dd0] = u;
      }
    }
  }
}

// ---------------- flash attention ----------------
// 4 waves x 32 q-rows = 128 rows/block; 512 blocks; 2 blocks/CU (LDS 64KB).
// 32x32x16 MFMA; in-register P exchange (no lP).
__global__ __launch_bounds__(256, 2) void k_flash(
    const unsigned short* __restrict__ Qs, const unsigned short* __restrict__ Ks,
    const unsigned short* __restrict__ Vt,
    const unsigned long long* __restrict__ mbits,
    unsigned short* __restrict__ Ob) {
  __shared__ __align__(16) unsigned short lK[2][16][64][8];   // 2 x 16 KB
  __shared__ __align__(16) unsigned short lV[2][8][128][8];   // 2 x 16 KB

  const int tid = threadIdx.x;
  const int w = tid >> 6, ln = tid & 63;
  const int l31 = ln & 31, hi = ln >> 5, hi4 = hi << 2;
  const bool hib = hi != 0;
  const int id = blockIdx.x;
  const int xcd = id & 7, jj = id >> 3;           // 64 blocks per XCD
  const int bh = (xcd << 1) | (jj >> 5);          // 2 bh per XCD (4MB K/V in L2)
  const int rowblk = jj & 31;
  const int rbase = rowblk * 128 + w * 32;
  const int qrow = rbase + l31;

  const unsigned short* Qbh = Qs + (long)bh * 524288;
  const unsigned short* Kbh = Ks + (long)bh * 524288;
  const unsigned short* Vbh = Vt + (long)bh * 524288;

  // Q as B-frag of mfma32(K, Q): lane(col=q=l31, hi) holds k = hi*8+e per step
  short8 qf[8];
#pragma unroll
  for (int ks = 0; ks < 8; ++ks)
    qf[ks] = *(const short8*)(Qbh + (long)qrow * 128 + ks * 16 + hi * 8);

  f32x16 o[4];
#pragma unroll
  for (int d = 0; d < 4; ++d)
#pragma unroll
    for (int r = 0; r < 16; ++r) o[d][r] = 0.f;
  float lacc = 0.f;

  const bool maskblk = rowblk < 16;   // rows 0..2047

#define STAGE_KV(dst, kvoff)                                              \
  {                                                                       \
    _Pragma("unroll")                                                     \
    for (int c = 0; c < 4; ++c) {                                         \
      const int p = ((c * 4 + w) << 10) + (ln << 4);                      \
      const int cs = p >> 10;                                             \
      const int j = (p & 1023) >> 4;                                      \
      gload_lds16(Kbh + (long)((kvoff) + j) * 128 + cs * 8,               \
                  (char*)&lK[dst][0][0][0] + p);                          \
    }                                                                     \
    _Pragma("unroll")                                                     \
    for (int c = 0; c < 4; ++c) {                                         \
      const int p = ((c * 4 + w) << 10) + (ln << 4);                      \
      const int cv = p >> 11;                                             \
      const int dv = (p & 2047) >> 4;                                     \
      gload_lds16(Vbh + (long)dv * 4096 + (kvoff) + cv * 8,               \
                  (char*)&lV[dst][0][0][0] + p);                          \
    }                                                                     \
  }

  // half-exchange across lane<32/lane>=32 (permlane32_swap semantics):
  // newA = (loA, loB), newB = (hiA, hiB)
#define PLSWAP(a, b)                                                      \
  {                                                                       \
    const unsigned pa_ = (unsigned)__shfl_xor((int)(a), 32);              \
    const unsigned pb_ = (unsigned)__shfl_xor((int)(b), 32);              \
    const unsigned na_ = hib ? pb_ : (a);                                 \
    const unsigned nb_ = hib ? (b) : pa_;                                 \
    (a) = na_; (b) = nb_;                                                 \
  }

  STAGE_KV(0, 0);
  __syncthreads();

  int cur = 0;
  for (int kv = 0; kv < 4096; kv += 64) {
    unsigned long long mw = 0ull;
    const bool domask = maskblk && (kv < 2048);
    if (domask) mw = mbits[(long)qrow * 32 + (kv >> 6)];

    const int nb = cur ^ 1;
    if (kv + 64 < 4096) STAGE_KV(nb, kv + 64);

    // S^T tiles: s0 = kv[0..31], s1 = kv[32..63]; col=q=l31,
    // row(kv_local) = (r&3) + 8*(r>>2) + 4*hi
    f32x16 s0, s1;
#pragma unroll
    for (int r = 0; r < 16; ++r) { s0[r] = 0.f; s1[r] = 0.f; }
    __builtin_amdgcn_s_setprio(1);
#pragma unroll
    for (int ks = 0; ks < 8; ++ks) {
      const short8 kf0 = *(const short8*)&lK[cur][ks * 2 + hi][l31][0];
      const short8 kf1 = *(const short8*)&lK[cur][ks * 2 + hi][32 + l31][0];
      s0 = __builtin_amdgcn_mfma_f32_32x32x16_bf16(kf0, qf[ks], s0, 0, 0, 0);
      s1 = __builtin_amdgcn_mfma_f32_32x32x16_bf16(kf1, qf[ks], s1, 0, 0, 0);
    }
    __builtin_amdgcn_s_setprio(0);

    if (domask) {
      const unsigned mlo = ((unsigned)mw) >> hi4;
      const unsigned mhi = ((unsigned)(mw >> 32)) >> hi4;
#pragma unroll
      for (int r = 0; r < 16; ++r) {
        const int c = ((r >> 2) << 3) + (r & 3);
        if (!((mlo >> c) & 1u)) s0[r] = -1e30f;
        if (!((mhi >> c) & 1u)) s1[r] = -1e30f;
      }
    }

    // p = exp2(s); rowsum partial (union over hi-halves covers all 64 kv)
    float p0[16], p1[16];
#pragma unroll
    for (int r = 0; r < 16; ++r) {
      p0[r] = __builtin_amdgcn_exp2f(s0[r]);
      p1[r] = __builtin_amdgcn_exp2f(s1[r]);
      lacc += p0[r] + p1[r];
    }

    // pack to bf16 + half-swap -> PV A-frags (k = hi*8+e per 16-kv step)
    unsigned w00 = pkbf2(p0[0], p0[1]),   w01 = pkbf2(p0[2], p0[3]);
    unsigned w10 = pkbf2(p0[4], p0[5]),   w11 = pkbf2(p0[6], p0[7]);
    PLSWAP(w00, w10); PLSWAP(w01, w11);
    unsigned w20 = pkbf2(p0[8], p0[9]),   w21 = pkbf2(p0[10], p0[11]);
    unsigned w30 = pkbf2(p0[12], p0[13]), w31 = pkbf2(p0[14], p0[15]);
    PLSWAP(w20, w30); PLSWAP(w21, w31);
    unsigned x00 = pkbf2(p1[0], p1[1]),   x01 = pkbf2(p1[2], p1[3]);
    unsigned x10 = pkbf2(p1[4], p1[5]),   x11 = pkbf2(p1[6], p1[7]);
    PLSWAP(x00, x10); PLSWAP(x01, x11);
    unsigned x20 = pkbf2(p1[8], p1[9]),   x21 = pkbf2(p1[10], p1[11]);
    unsigned x30 = pkbf2(p1[12], p1[13]), x31 = pkbf2(p1[14], p1[15]);
    PLSWAP(x20, x30); PLSWAP(x21, x31);

    union { unsigned u[4]; short8 s; } pa0, pa1, pa2, pa3;
    pa0.u[0] = w00; pa0.u[1] = w01; pa0.u[2] = w10; pa0.u[3] = w11;
    pa1.u[0] = w20; pa1.u[1] = w21; pa1.u[2] = w30; pa1.u[3] = w31;
    pa2.u[0] = x00; pa2.u[1] = x01; pa2.u[2] = x10; pa2.u[3] = x11;
    pa3.u[0] = x20; pa3.u[1] = x21; pa3.u[2] = x30; pa3.u[3] = x31;
    const short8 pa[4] = {pa0.s, pa1.s, pa2.s, pa3.s};

    // O += P @ V  : B-frag lane(col=d=l31, hi) holds V[kv=hi*8+e][d]
    __builtin_amdgcn_s_setprio(1);
#pragma unroll
    for (int ksl = 0; ksl < 4; ++ksl) {
#pragma unroll
      for (int db = 0; db < 4; ++db) {
        const short8 vf =
            *(const short8*)&lV[cur][ksl * 2 + hi][db * 32 + l31][0];
        o[db] = __builtin_amdgcn_mfma_f32_32x32x16_bf16(pa[ksl], vf,
                                                        o[db], 0, 0, 0);
      }
    }
    __builtin_amdgcn_s_setprio(0);

    __syncthreads();
    cur = nb;
  }
#undef STAGE_KV
#undef PLSWAP

  // l[q] = own half + partner half; linv lives at lane q (both halves)
  const float lh = lacc + __shfl_xor(lacc, 32);
  const float linv = 1.0f / lh;

  const int b = bh >> 3, h = bh & 7;
#pragma unroll
  for (int r = 0; r < 16; ++r) {
    const int qr = (r & 3) + ((r >> 2) << 3) + hi4;
    const float li = __shfl(linv, qr);
    const int row = rbase + qr;
    unsigned short* op = Ob + ((long)(b * 4096 + row)) * 1024 + h * 128 + l31;
#pragma unroll
    for (int db = 0; db < 4; ++db)
      op[db * 32] = f2bf(o[db][r] * li);
  }
}

// ---------------- out projection ----------------
__global__ __launch_bounds__(256, 2) void k_proj_gemm(
    const unsigned short* __restrict__ A,   // [8192][1024]
    const unsigned short* __restrict__ Bt,  // [1024][1024]
    const float* __restrict__ bias, float* __restrict__ Out) {
  __shared__ __align__(16) unsigned short lA[4][128][8];
  __shared__ __align__(16) unsigned short lB[4][128][8];
  const int tid = threadIdx.x;
  const int w = tid >> 6, ln = tid & 63;
  const int m15 = ln & 15, q4 = ln >> 4;
  const int wm = (w >> 1) << 6, wn = (w & 1) << 6;
  const int id = blockIdx.x;
  const int swz = (id & 7) * 64 + (id >> 3);
  const int tn = swz & 7, tm = swz >> 3;

  f32x4 acc[4][4];
#pragma unroll
  for (int i = 0; i < 4; ++i)
#pragma unroll
    for (int j = 0; j < 4; ++j) acc[i][j] = zero4();

  for (int kb = 0; kb < 1024; kb += 32) {
    __syncthreads();
#pragma unroll
    for (int c = 0; c < 2; ++c) {
      const int p = ((c * 4 + w) << 10) + (ln << 4);
      const int g = p >> 11;
      const int r = (p & 2047) >> 4;
      gload_lds16(A + ((long)tm * 128 + r) * 1024 + kb + g * 8,
                  (char*)&lA[0][0][0] + p);
      gload_lds16(Bt + ((long)tn * 128 + r) * 1024 + kb + g * 8,
                  (char*)&lB[0][0][0] + p);
    }
    __syncthreads();
    short8 afr[4], bfr[4];
#pragma unroll
    for (int i = 0; i < 4; ++i)
      afr[i] = *(const short8*)&lA[q4][wm + i * 16 + m15][0];
#pragma unroll
    for (int j = 0; j < 4; ++j)
      bfr[j] = *(const short8*)&lB[q4][wn + j * 16 + m15][0];
#pragma unroll
    for (int i = 0; i < 4; ++i)
#pragma unroll
      for (int j = 0; j < 4; ++j)
        acc[i][j] = __builtin_amdgcn_mfma_f32_16x16x32_bf16(afr[i], bfr[j],
                                                            acc[i][j], 0, 0, 0);
  }

#pragma unroll
  for (int i = 0; i < 4; ++i)
#pragma unroll
    for (int r = 0; r < 4; ++r) {
      const int m = (tm << 7) + wm + (i << 4) + (q4 << 2) + r;
#pragma unroll
      for (int j = 0; j < 4; ++j) {
        const int n = (tn << 7) + wn + (j << 4) + m15;
        Out[(long)m * 1024 + n] = acc[i][j][r] + bias[n];
      }
    }
}

extern "C" void kernel_launch(void* const* d_in, const int* in_sizes, int n_in,
                              void* d_out, int out_size, void* d_ws,
                              size_t ws_size, hipStream_t stream) {
  const float* x = (const float*)d_in[0];
  const float* Wqkv = (const float*)d_in[1];
  const float* Wout = (const float*)d_in[2];
  const float* bout = (const float*)d_in[3];
  const int* mask = (const int*)d_in[4];
  float* out = (float*)d_out;

  char* ws = (char*)d_ws;
  unsigned short* xb     = (unsigned short*)(ws);            // later Ob
  unsigned short* wqkv_t = (unsigned short*)(ws + 16777216);
  unsigned short* wout_t = (unsigned short*)(ws + 23068672);
  unsigned short* Qs     = (unsigned short*)(ws + 25165824);
  unsigned short* Ks     = (unsigned short*)(ws + 41943040);
  unsigned short* Vt     = (unsigned short*)(ws + 58720256);
  unsigned short* Ob     = xb;                         // xb dead after qkv
  unsigned long long* mbits = (unsigned long long*)wqkv_t;  // wqkv_t dead after qkv

  hipLaunchKernelGGL(k_cvt_x, dim3(8192), dim3(256), 0, stream, x, xb);
  hipLaunchKernelGGL(k_cvt_wt, dim3(96, 32), dim3(256), 0, stream, Wqkv, wqkv_t, 3072);
  hipLaunchKernelGGL(k_cvt_wt, dim3(32, 32), dim3(256), 0, stream, Wout, wout_t, 1024);
  hipLaunchKernelGGL(k_qkv_gemm, dim3(1536), dim3(256), 0, stream,
                     xb, wqkv_t, Qs, Ks, Vt);
  hipLaunchKernelGGL(k_mask_bits, dim3(16384), dim3(256), 0, stream,
                     mask, mbits);
  hipLaunchKernelGGL(k_flash, dim3(512), dim3(256), 0, stream,
                     Qs, Ks, Vt, mbits, Ob);
  hipLaunchKernelGGL(k_proj_gemm, dim3(512), dim3(256), 0, stream,
                     Ob, wout_t, bout, out);
}